// Round 11
// baseline (256.199 us; speedup 1.0000x reference)
//
#include <hip/hip_runtime.h>

// NeuralFieldCosmo — R11: R10 dual-tile (verified correct, absmax 0.047) +
// amdgpu_waves_per_eu(2,2) to unlock the 128->256 VGPR band.
// R10 evidence: VGPR pinned at 128, FETCH +250MB = ~18 regs spilled per
// iteration (9.6KB/iter). Allocator won't cross the 4->2 waves/SIMD cliff
// voluntarily; pinning max-waves=2 removes its reason to spill.
// Ledger: cvt_pk inline-asm pack = NaN source (R8/R9) — banned from value
// path. f2bf RNE pack verified R4-R10. MFMA 16x16x16bf16 layout verified.

typedef __attribute__((ext_vector_type(4))) short short4v;   // 4 bf16
typedef __attribute__((ext_vector_type(4))) float float4v;
typedef __attribute__((ext_vector_type(4))) unsigned uint4v;
typedef __attribute__((ext_vector_type(2))) unsigned uint2v;

constexpr float LN_EPS   = 1e-5f;
constexpr float LOG2E_X2 = 2.8853900817779268f;  // 2*log2(e)

// RNE float -> bf16 bits (verified R4-R10)
__device__ __forceinline__ unsigned f2bf(float x) {
  unsigned u = __builtin_bit_cast(unsigned, x);
  u += 0x7FFFu + ((u >> 16) & 1u);
  return u >> 16;
}
__device__ __forceinline__ unsigned pack2(float lo, float hi) {
  return f2bf(lo) | (f2bf(hi) << 16);
}
__device__ __forceinline__ float bflo2f(unsigned u) {
  return __builtin_bit_cast(float, u << 16);
}
__device__ __forceinline__ float bfhi2f(unsigned u) {
  return __builtin_bit_cast(float, u & 0xFFFF0000u);
}

__device__ __forceinline__ float4v mfma16(short4v a, short4v b, float4v c) {
#if __has_builtin(__builtin_amdgcn_mfma_f32_16x16x16bf16_1k)
  return __builtin_amdgcn_mfma_f32_16x16x16bf16_1k(a, b, c, 0, 0, 0);
#else
  float4v d;
  asm volatile("v_mfma_f32_16x16x16_bf16 %0, %1, %2, %3\n\ts_nop 7\n\ts_nop 7"
               : "=&v"(d) : "v"(a), "v"(b), "v"(c));
  return d;
#endif
}

// LN over 32 ch (8/lane across quads), affine (packed bf16 g,be), relu,
// pack to two K-half B-frags. IDENTICAL to R7/R10 (verified).
__device__ __forceinline__ void ln_relu_pack(const float* hv, uint4v gp,
                                             uint4v bp, short4v* bh) {
  float sum = 0.f, ss = 0.f;
#pragma unroll
  for (int s = 0; s < 8; ++s) { sum += hv[s]; ss += hv[s] * hv[s]; }
  sum += __shfl_xor(sum, 16);  ss += __shfl_xor(ss, 16);
  sum += __shfl_xor(sum, 32);  ss += __shfl_xor(ss, 32);
  const float m   = sum * (1.0f / 32.0f);
  const float var = fmaxf(ss * (1.0f / 32.0f) - m * m, 0.f);
  const float rs  = rsqrtf(var + LN_EPS);
#pragma unroll
  for (int h = 0; h < 2; ++h) {
    short4v v;
#pragma unroll
    for (int j = 0; j < 4; ++j) {
      const int s = h * 4 + j;
      const float g  = (s & 1) ? bfhi2f(gp[s >> 1]) : bflo2f(gp[s >> 1]);
      const float be = (s & 1) ? bfhi2f(bp[s >> 1]) : bflo2f(bp[s >> 1]);
      float y = (hv[s] - m) * rs * g + be;
      v[j] = (short)f2bf(fmaxf(y, 0.f));
    }
    bh[h] = v;
  }
}

// ---------------- CSR build ----------------

__global__ void nf_hist(const int* __restrict__ out_edges, int* __restrict__ counts, int E) {
  int stride = gridDim.x * blockDim.x;
  for (int e = blockIdx.x * blockDim.x + threadIdx.x; e < E; e += stride)
    atomicAdd(&counts[out_edges[e]], 1);
}

__global__ void nf_alloc(const int* __restrict__ counts, int* __restrict__ offsets,
                         int* __restrict__ cursor, int* __restrict__ total, int N) {
  const int i = blockIdx.x * blockDim.x + threadIdx.x;
  const int lane = threadIdx.x & 63;
  int c = (i < N) ? counts[i] : 0;
  int sc = c;
#pragma unroll
  for (int d = 1; d < 64; d <<= 1) {
    int v = __shfl_up(sc, d);
    if (lane >= d) sc += v;
  }
  const int excl = sc - c;
  const int wtot = __shfl(sc, 63);
  int base = 0;
  if (lane == 0) base = atomicAdd(total, wtot);
  base = __shfl(base, 0);
  if (i < N) {
    offsets[i] = base + excl;
    cursor[i]  = base + excl;
  }
}

// ---------------- main compute ----------------
// SCATTER_MODE: 0 = CSR-ordered stream, 1 = direct atomics fallback

template <int SCATTER_MODE>
__global__ __attribute__((amdgpu_waves_per_eu(2, 2)))
__launch_bounds__(256)
void nf_main(const int* __restrict__ in_edges,
             const int* __restrict__ out_edges,
             const float* __restrict__ ef,
             const float* __restrict__ coords,
             const float* __restrict__ W1, const float* __restrict__ b1,
             const float* __restrict__ g1, const float* __restrict__ be1,
             const float* __restrict__ W2, const float* __restrict__ b2,
             const float* __restrict__ g2, const float* __restrict__ be2,
             const float* __restrict__ W3, const float* __restrict__ b3,
             float* __restrict__ out_ch,  // mode0: [E][16] CSR-ordered ; mode1: sums (d_out)
             int* __restrict__ aux,       // mode1: counts
             int* __restrict__ cursor,    // mode0: [N]
             int E, int ntiles)
{
  // W3 A-fragments (prescaled 2log2e), per (o, lane): 16B = 8 bf16 {k=4q+j+16h}
  __shared__ __align__(16) unsigned sA3[16 * 64 * 4];   // 16 KB
  __shared__ __align__(16) float    sB3f[16 * 4 * 4];   // 2log2e*b3, f32
  __shared__ __align__(16) unsigned sC1[4][16];  // w1p[3][4], b1p[4]
  __shared__ __align__(16) unsigned sC2[4][16];  // g1p, be1p, g2p, be2p
  __shared__ __align__(16) unsigned sC3[4][4];   // b2p

  const int t    = threadIdx.x;
  const int l    = t & 63;
  const int q    = l >> 4;     // lane quad (channel/row group)
  const int ecol = l & 15;     // edge column within tile

  // ---- one-time LDS staging (identical to R7/R10, verified) ----
#pragma unroll
  for (int rep = 0; rep < 4; ++rep) {
    const int idx = rep * 256 + t;          // (o, lane)
    const int o = idx >> 6, ll = idx & 63;
    const int qq = ll >> 4, ec = ll & 15;
    uint4v w;
#pragma unroll
    for (int h = 0; h < 2; ++h)
#pragma unroll
      for (int jp = 0; jp < 2; ++jp) {
        const float lo = LOG2E_X2 * W3[(4 * qq + 2 * jp     + 16 * h) * 256 + o * 16 + ec];
        const float hi = LOG2E_X2 * W3[(4 * qq + 2 * jp + 1 + 16 * h) * 256 + o * 16 + ec];
        w[h * 2 + jp] = pack2(lo, hi);
      }
    *(uint4v*)&sA3[idx * 4] = w;
  }
  if (t < 64) {
    const int o = t >> 2, qq = t & 3;
    float4v bb;
#pragma unroll
    for (int r = 0; r < 4; ++r) bb[r] = LOG2E_X2 * b3[o * 16 + 4 * qq + r];
    *(float4v*)&sB3f[t * 4] = bb;
  }
  if (t < 4) {
    const int qq = t;
#pragma unroll
    for (int i = 0; i < 4; ++i) {
      const int base = (i < 2) ? (4 * qq + 2 * i) : (4 * qq + 16 + 2 * (i - 2));
      sC1[qq][i]      = pack2(W1[base],      W1[base + 1]);
      sC1[qq][4 + i]  = pack2(W1[32 + base], W1[33 + base]);
      sC1[qq][8 + i]  = pack2(W1[64 + base], W1[65 + base]);
      sC1[qq][12 + i] = pack2(b1[base],      b1[base + 1]);
      sC2[qq][i]      = pack2(g1[base],      g1[base + 1]);
      sC2[qq][4 + i]  = pack2(be1[base],     be1[base + 1]);
      sC2[qq][8 + i]  = pack2(g2[base],      g2[base + 1]);
      sC2[qq][12 + i] = pack2(be2[base],     be2[base + 1]);
      sC3[qq][i]      = pack2(b2[base],      b2[base + 1]);
    }
  }

  // L2 A-frags in regs (8 VGPR): A[m=ch_out][k=ch_in] = W2[k][m]
  short4v a2[2][2];
#pragma unroll
  for (int t2 = 0; t2 < 2; ++t2)
#pragma unroll
    for (int h = 0; h < 2; ++h) {
      short4v v;
#pragma unroll
      for (int j = 0; j < 4; ++j)
        v[j] = (short)f2bf(W2[(4 * q + j + 16 * h) * 32 + ecol + 16 * t2]);
      a2[t2][h] = v;
    }

  __syncthreads();

  // front half: L1 -> LN1 -> L2 -> LN2 -> bh[2] (body identical to R7/R10)
  auto front = [&](float x0, float x1, float x2, short4v* bh) {
    const uint4v w1r0 = *(const uint4v*)&sC1[q][0];
    const uint4v w1r1 = *(const uint4v*)&sC1[q][4];
    const uint4v w1r2 = *(const uint4v*)&sC1[q][8];
    const uint4v b1v  = *(const uint4v*)&sC1[q][12];
    float hv[8];
#pragma unroll
    for (int i = 0; i < 4; ++i) {
      hv[2 * i]     = bflo2f(b1v[i]) + x0 * bflo2f(w1r0[i])
                    + x1 * bflo2f(w1r1[i]) + x2 * bflo2f(w1r2[i]);
      hv[2 * i + 1] = bfhi2f(b1v[i]) + x0 * bfhi2f(w1r0[i])
                    + x1 * bfhi2f(w1r1[i]) + x2 * bfhi2f(w1r2[i]);
    }
    {
      const uint4v g1v  = *(const uint4v*)&sC2[q][0];
      const uint4v be1v = *(const uint4v*)&sC2[q][4];
      ln_relu_pack(hv, g1v, be1v, bh);
    }
    {
      const uint4v b2v = *(const uint4v*)&sC3[q][0];
#pragma unroll
      for (int t2 = 0; t2 < 2; ++t2) {
        float4v c;
        c[0] = bflo2f(b2v[t2 * 2]);     c[1] = bfhi2f(b2v[t2 * 2]);
        c[2] = bflo2f(b2v[t2 * 2 + 1]); c[3] = bfhi2f(b2v[t2 * 2 + 1]);
        c = mfma16(a2[t2][0], bh[0], c);
        c = mfma16(a2[t2][1], bh[1], c);
        hv[t2 * 4 + 0] = c[0]; hv[t2 * 4 + 1] = c[1];
        hv[t2 * 4 + 2] = c[2]; hv[t2 * 4 + 3] = c[3];
      }
    }
    {
      const uint4v g2v  = *(const uint4v*)&sC2[q][8];
      const uint4v be2v = *(const uint4v*)&sC2[q][12];
      ln_relu_pack(hv, g2v, be2v, bh);
    }
  };

  const int gwave  = (blockIdx.x * blockDim.x + t) >> 6;
  const int nwaves = (gridDim.x * blockDim.x) >> 6;
  const int stride = 2 * nwaves;

  // ---- prologue: pair-0 state (A = gwave, B = gwave + nwaves) ----
  int tile = gwave;
  bool validA = false, validB = false;
  int oeA = 0, oeB = 0;
  float xA0 = 0.f, xA1 = 0.f, xA2 = 0.f, xB0 = 0.f, xB1 = 0.f, xB2 = 0.f;
  float4v f4A = {}, f4B = {};
  if (tile < ntiles) {
    const int eI = tile * 16 + ecol;
    validA = eI < E;
    const int eS = validA ? eI : 0;
    const int ie = in_edges[eS]; oeA = out_edges[eS];
    xA0 = coords[3 * eS]; xA1 = coords[3 * eS + 1]; xA2 = coords[3 * eS + 2];
    f4A = *(const float4v*)(ef + (size_t)ie * 16 + 4 * q);
  }
  if (tile + nwaves < ntiles) {
    const int eI = (tile + nwaves) * 16 + ecol;
    validB = eI < E;
    const int eS = validB ? eI : 0;
    const int ie = in_edges[eS]; oeB = out_edges[eS];
    xB0 = coords[3 * eS]; xB1 = coords[3 * eS + 1]; xB2 = coords[3 * eS + 2];
    f4B = *(const float4v*)(ef + (size_t)ie * 16 + 4 * q);
  }

  for (; tile < ntiles; tile += stride) {
    // ---- prefetch next pair's indices + coords ----
    const int tA2 = tile + stride, tB2 = tile + stride + nwaves;
    bool validA2 = false, validB2 = false;
    int ieA2 = 0, ieB2 = 0, oeA2 = 0, oeB2 = 0;
    float xA0N = 0.f, xA1N = 0.f, xA2N = 0.f, xB0N = 0.f, xB1N = 0.f, xB2N = 0.f;
    if (tA2 < ntiles) {
      const int eI = tA2 * 16 + ecol;
      validA2 = eI < E;
      const int eS = validA2 ? eI : 0;
      ieA2 = in_edges[eS]; oeA2 = out_edges[eS];
      xA0N = coords[3 * eS]; xA1N = coords[3 * eS + 1]; xA2N = coords[3 * eS + 2];
    }
    if (tB2 < ntiles) {
      const int eI = tB2 * 16 + ecol;
      validB2 = eI < E;
      const int eS = validB2 ? eI : 0;
      ieB2 = in_edges[eS]; oeB2 = out_edges[eS];
      xB0N = coords[3 * eS]; xB1N = coords[3 * eS + 1]; xB2N = coords[3 * eS + 2];
    }

    // CSR slots (atomic latency hides under the MLP)
    int posA = 0, posB = 0;
    if (SCATTER_MODE == 0 && q == 0) {
      if (validA) posA = atomicAdd(&cursor[oeA], 1);
      if (validB) posB = atomicAdd(&cursor[oeB], 1);
    }

    // ---- front halves: two independent chains interleave ----
    short4v bhA[2], bhB[2];
    front(xA0, xA1, xA2, bhA);
    front(xB0, xB1, xB2, bhB);

    // ---- prefetch next pair's feature gathers (indices landed) ----
    float4v f4AN = {}, f4BN = {};
    if (tA2 < ntiles) f4AN = *(const float4v*)(ef + (size_t)ieA2 * 16 + 4 * q);
    if (tB2 < ntiles) f4BN = *(const float4v*)(ef + (size_t)ieB2 * 16 + 4 * q);

    const float sumfA = (f4A[0] + f4A[1]) + (f4A[2] + f4A[3]);
    const float sumfB = (f4B[0] + f4B[1]) + (f4B[2] + f4B[3]);

    // ---- L3 + epilogue: shared ds_reads feed both tiles ----
#pragma unroll
    for (int og = 0; og < 4; ++og) {
      float prA[4], prB[4];
#pragma unroll
      for (int r = 0; r < 4; ++r) {
        const int o = og * 4 + r;
        const uint4v av = *(const uint4v*)&sA3[(o * 64 + l) * 4];
        const float4v ci = *(const float4v*)&sB3f[(o * 4 + q) * 4];
        uint2v t0; t0[0] = av[0]; t0[1] = av[1];
        uint2v t1; t1[0] = av[2]; t1[1] = av[3];
        const short4v a30 = __builtin_bit_cast(short4v, t0);
        const short4v a31 = __builtin_bit_cast(short4v, t1);
        float4v cA = ci, cB = ci;
        cA = mfma16(a30, bhA[0], cA);
        cB = mfma16(a30, bhB[0], cB);
        cA = mfma16(a31, bhA[1], cA);
        cB = mfma16(a31, bhB[1], cB);
        float dA = 0.f, dB = 0.f;
#pragma unroll
        for (int j = 0; j < 4; ++j) {
          const float eA = __builtin_amdgcn_exp2f(cA[j]);
          const float eB = __builtin_amdgcn_exp2f(cB[j]);
          dA = fmaf(f4A[j], __builtin_amdgcn_rcpf(eA + 1.0f), dA);
          dB = fmaf(f4B[j], __builtin_amdgcn_rcpf(eB + 1.0f), dB);
        }
        prA[r] = fmaf(-2.0f, dA, sumfA);
        prB[r] = fmaf(-2.0f, dB, sumfB);
      }
#pragma unroll
      for (int r = 0; r < 4; ++r) {
        prA[r] += __shfl_xor(prA[r], 16);
        prA[r] += __shfl_xor(prA[r], 32);
        prB[r] += __shfl_xor(prB[r], 16);
        prB[r] += __shfl_xor(prB[r], 32);
      }
      if (SCATTER_MODE == 0) {
        if (q == 0 && validA) {
          float4v s = {prA[0], prA[1], prA[2], prA[3]};
          *(float4v*)(out_ch + (size_t)posA * 16 + og * 4) = s;
        }
        if (q == 0 && validB) {
          float4v s = {prB[0], prB[1], prB[2], prB[3]};
          *(float4v*)(out_ch + (size_t)posB * 16 + og * 4) = s;
        }
      } else {
        if (q == 0 && validA) {
#pragma unroll
          for (int r = 0; r < 4; ++r)
            atomicAdd(&out_ch[(size_t)oeA * 16 + og * 4 + r], prA[r]);
        }
        if (q == 0 && validB) {
#pragma unroll
          for (int r = 0; r < 4; ++r)
            atomicAdd(&out_ch[(size_t)oeB * 16 + og * 4 + r], prB[r]);
        }
      }
    }
    if (SCATTER_MODE == 1 && q == 0) {
      if (validA) atomicAdd(&aux[oeA], 1);
      if (validB) atomicAdd(&aux[oeB], 1);
    }

    // rotate pipeline state
    validA = validA2; validB = validB2; oeA = oeA2; oeB = oeB2;
    xA0 = xA0N; xA1 = xA1N; xA2 = xA2N; xB0 = xB0N; xB1 = xB1N; xB2 = xB2N;
    f4A = f4AN; f4B = f4BN;
  }
}

// ---------------- per-node reduce (CSR path, contiguous rows) ----------------

__global__ __launch_bounds__(256)
void nf_reduce(const float* __restrict__ out_ch, const int* __restrict__ counts,
               const int* __restrict__ offsets, float* __restrict__ out, int N) {
  const int gid = blockIdx.x * 16 + (threadIdx.x >> 4);
  const int o   = threadIdx.x & 15;
  if (gid >= N) return;
  const int deg = counts[gid];
  const int off = offsets[gid];
  float acc = 0.f;
  for (int d = 0; d < deg; ++d)
    acc += out_ch[(size_t)(off + d) * 16 + o];
  out[(size_t)gid * 16 + o] = acc / fmaxf((float)deg, 1.0f);
}

__global__ void nf_final(float* __restrict__ out, const int* __restrict__ counts, int n) {
  int i = blockIdx.x * blockDim.x + threadIdx.x;
  if (i < n) {
    float c = (float)counts[i >> 4];
    out[i] = out[i] / fmaxf(c, 1.0f);
  }
}

extern "C" void kernel_launch(void* const* d_in, const int* in_sizes, int n_in,
                              void* d_out, int out_size, void* d_ws, size_t ws_size,
                              hipStream_t stream) {
  const int*   in_edges  = (const int*)d_in[0];
  const int*   out_edges = (const int*)d_in[1];
  const float* ef        = (const float*)d_in[2];
  const float* coords    = (const float*)d_in[3];
  const float* W1  = (const float*)d_in[4];
  const float* b1  = (const float*)d_in[5];
  const float* g1  = (const float*)d_in[6];
  const float* be1 = (const float*)d_in[7];
  const float* W2  = (const float*)d_in[8];
  const float* b2  = (const float*)d_in[9];
  const float* g2  = (const float*)d_in[10];
  const float* be2 = (const float*)d_in[11];
  const float* W3  = (const float*)d_in[12];
  const float* b3  = (const float*)d_in[13];

  const int E = in_sizes[0];
  const int N = in_sizes[2] / 16;
  const int ntiles = (E + 15) / 16;
  float* out = (float*)d_out;

  // ws: out_ch [16E f32] | counts [N] | offsets [N] | cursor [N] | total [1]
  const size_t need = ((size_t)E * 16 + 3 * (size_t)N + 1) * 4;

  if (ws_size >= need) {
    float* out_chv = (float*)d_ws;
    int*   counts  = (int*)(out_chv + (size_t)E * 16);
    int*   offsets = counts + N;
    int*   cursor  = offsets + N;
    int*   total   = cursor + N;

    hipMemsetAsync(counts, 0, ((size_t)3 * N + 1) * sizeof(int), stream);
    nf_hist<<<1024, 256, 0, stream>>>(out_edges, counts, E);
    nf_alloc<<<(N + 255) / 256, 256, 0, stream>>>(counts, offsets, cursor, total, N);
    nf_main<0><<<1024, 256, 0, stream>>>(in_edges, out_edges, ef, coords,
                                         W1, b1, g1, be1, W2, b2, g2, be2, W3, b3,
                                         out_chv, nullptr, cursor, E, ntiles);
    nf_reduce<<<(N + 15) / 16, 256, 0, stream>>>(out_chv, counts, offsets, out, N);
  } else {
    int* counts = (int*)d_ws;
    hipMemsetAsync(out, 0, (size_t)out_size * sizeof(float), stream);
    hipMemsetAsync(counts, 0, (size_t)N * sizeof(int), stream);
    nf_main<1><<<1024, 256, 0, stream>>>(in_edges, out_edges, ef, coords,
                                         W1, b1, g1, be1, W2, b2, g2, be2, W3, b3,
                                         out, counts, nullptr, E, ntiles);
    nf_final<<<(out_size + 255) / 256, 256, 0, stream>>>(out, counts, out_size);
  }
}

// Round 12
// 242.248 us; speedup vs baseline: 1.0576x; 1.0576x over previous
//
#include <hip/hip_runtime.h>

// NeuralFieldCosmo — R12: dual-tile (R10-verified numerics) with a trimmed
// live set to fit the 128-VGPR band honestly.
// R10: dual-tile spilled ~18 regs (FETCH 62->311MB) at VGPR=128.
// R11: amdgpu_waves_per_eu(2,2) ignored (counters unchanged) — reverted.
// R12 trim: pair = ADJACENT tiles (contiguous 32-edge segment); carry only
// indices+coords across iterations (~12 regs, was ~28+8); f4 gathers issue
// at loop top from last iteration's prefetched indices (never carried).
// Ledger: cvt_pk inline-asm pack = NaN (R8/R9, banned). f2bf RNE verified.
// MFMA 16x16x16bf16 layout verified R4-R11. launch_bounds(256,2) + consts
// in LDS = spill-free at <=128 live (R6/R7).

typedef __attribute__((ext_vector_type(4))) short short4v;   // 4 bf16
typedef __attribute__((ext_vector_type(4))) float float4v;
typedef __attribute__((ext_vector_type(4))) unsigned uint4v;
typedef __attribute__((ext_vector_type(2))) unsigned uint2v;

constexpr float LN_EPS   = 1e-5f;
constexpr float LOG2E_X2 = 2.8853900817779268f;  // 2*log2(e)

// RNE float -> bf16 bits (verified R4-R11)
__device__ __forceinline__ unsigned f2bf(float x) {
  unsigned u = __builtin_bit_cast(unsigned, x);
  u += 0x7FFFu + ((u >> 16) & 1u);
  return u >> 16;
}
__device__ __forceinline__ unsigned pack2(float lo, float hi) {
  return f2bf(lo) | (f2bf(hi) << 16);
}
__device__ __forceinline__ float bflo2f(unsigned u) {
  return __builtin_bit_cast(float, u << 16);
}
__device__ __forceinline__ float bfhi2f(unsigned u) {
  return __builtin_bit_cast(float, u & 0xFFFF0000u);
}

__device__ __forceinline__ float4v mfma16(short4v a, short4v b, float4v c) {
#if __has_builtin(__builtin_amdgcn_mfma_f32_16x16x16bf16_1k)
  return __builtin_amdgcn_mfma_f32_16x16x16bf16_1k(a, b, c, 0, 0, 0);
#else
  float4v d;
  asm volatile("v_mfma_f32_16x16x16_bf16 %0, %1, %2, %3\n\ts_nop 7\n\ts_nop 7"
               : "=&v"(d) : "v"(a), "v"(b), "v"(c));
  return d;
#endif
}

// LN over 32 ch (8/lane across quads), affine (packed bf16 g,be), relu,
// pack to two K-half B-frags. IDENTICAL to R7/R10 (verified).
__device__ __forceinline__ void ln_relu_pack(const float* hv, uint4v gp,
                                             uint4v bp, short4v* bh) {
  float sum = 0.f, ss = 0.f;
#pragma unroll
  for (int s = 0; s < 8; ++s) { sum += hv[s]; ss += hv[s] * hv[s]; }
  sum += __shfl_xor(sum, 16);  ss += __shfl_xor(ss, 16);
  sum += __shfl_xor(sum, 32);  ss += __shfl_xor(ss, 32);
  const float m   = sum * (1.0f / 32.0f);
  const float var = fmaxf(ss * (1.0f / 32.0f) - m * m, 0.f);
  const float rs  = rsqrtf(var + LN_EPS);
#pragma unroll
  for (int h = 0; h < 2; ++h) {
    short4v v;
#pragma unroll
    for (int j = 0; j < 4; ++j) {
      const int s = h * 4 + j;
      const float g  = (s & 1) ? bfhi2f(gp[s >> 1]) : bflo2f(gp[s >> 1]);
      const float be = (s & 1) ? bfhi2f(bp[s >> 1]) : bflo2f(bp[s >> 1]);
      float y = (hv[s] - m) * rs * g + be;
      v[j] = (short)f2bf(fmaxf(y, 0.f));
    }
    bh[h] = v;
  }
}

// ---------------- CSR build ----------------

__global__ void nf_hist(const int* __restrict__ out_edges, int* __restrict__ counts, int E) {
  int stride = gridDim.x * blockDim.x;
  for (int e = blockIdx.x * blockDim.x + threadIdx.x; e < E; e += stride)
    atomicAdd(&counts[out_edges[e]], 1);
}

__global__ void nf_alloc(const int* __restrict__ counts, int* __restrict__ offsets,
                         int* __restrict__ cursor, int* __restrict__ total, int N) {
  const int i = blockIdx.x * blockDim.x + threadIdx.x;
  const int lane = threadIdx.x & 63;
  int c = (i < N) ? counts[i] : 0;
  int sc = c;
#pragma unroll
  for (int d = 1; d < 64; d <<= 1) {
    int v = __shfl_up(sc, d);
    if (lane >= d) sc += v;
  }
  const int excl = sc - c;
  const int wtot = __shfl(sc, 63);
  int base = 0;
  if (lane == 0) base = atomicAdd(total, wtot);
  base = __shfl(base, 0);
  if (i < N) {
    offsets[i] = base + excl;
    cursor[i]  = base + excl;
  }
}

// ---------------- main compute ----------------
// SCATTER_MODE: 0 = CSR-ordered stream, 1 = direct atomics fallback

template <int SCATTER_MODE>
__global__ __launch_bounds__(256, 2)
void nf_main(const int* __restrict__ in_edges,
             const int* __restrict__ out_edges,
             const float* __restrict__ ef,
             const float* __restrict__ coords,
             const float* __restrict__ W1, const float* __restrict__ b1,
             const float* __restrict__ g1, const float* __restrict__ be1,
             const float* __restrict__ W2, const float* __restrict__ b2,
             const float* __restrict__ g2, const float* __restrict__ be2,
             const float* __restrict__ W3, const float* __restrict__ b3,
             float* __restrict__ out_ch,  // mode0: [E][16] CSR-ordered ; mode1: sums (d_out)
             int* __restrict__ aux,       // mode1: counts
             int* __restrict__ cursor,    // mode0: [N]
             int E, int npairs)
{
  // W3 A-fragments (prescaled 2log2e), per (o, lane): 16B = 8 bf16 {k=4q+j+16h}
  __shared__ __align__(16) unsigned sA3[16 * 64 * 4];   // 16 KB
  __shared__ __align__(16) float    sB3f[16 * 4 * 4];   // 2log2e*b3, f32
  __shared__ __align__(16) unsigned sC1[4][16];  // w1p[3][4], b1p[4]
  __shared__ __align__(16) unsigned sC2[4][16];  // g1p, be1p, g2p, be2p
  __shared__ __align__(16) unsigned sC3[4][4];   // b2p

  const int t    = threadIdx.x;
  const int l    = t & 63;
  const int q    = l >> 4;     // lane quad (channel/row group)
  const int ecol = l & 15;     // edge column within tile

  // ---- one-time LDS staging (identical to R7/R10, verified) ----
#pragma unroll
  for (int rep = 0; rep < 4; ++rep) {
    const int idx = rep * 256 + t;          // (o, lane)
    const int o = idx >> 6, ll = idx & 63;
    const int qq = ll >> 4, ec = ll & 15;
    uint4v w;
#pragma unroll
    for (int h = 0; h < 2; ++h)
#pragma unroll
      for (int jp = 0; jp < 2; ++jp) {
        const float lo = LOG2E_X2 * W3[(4 * qq + 2 * jp     + 16 * h) * 256 + o * 16 + ec];
        const float hi = LOG2E_X2 * W3[(4 * qq + 2 * jp + 1 + 16 * h) * 256 + o * 16 + ec];
        w[h * 2 + jp] = pack2(lo, hi);
      }
    *(uint4v*)&sA3[idx * 4] = w;
  }
  if (t < 64) {
    const int o = t >> 2, qq = t & 3;
    float4v bb;
#pragma unroll
    for (int r = 0; r < 4; ++r) bb[r] = LOG2E_X2 * b3[o * 16 + 4 * qq + r];
    *(float4v*)&sB3f[t * 4] = bb;
  }
  if (t < 4) {
    const int qq = t;
#pragma unroll
    for (int i = 0; i < 4; ++i) {
      const int base = (i < 2) ? (4 * qq + 2 * i) : (4 * qq + 16 + 2 * (i - 2));
      sC1[qq][i]      = pack2(W1[base],      W1[base + 1]);
      sC1[qq][4 + i]  = pack2(W1[32 + base], W1[33 + base]);
      sC1[qq][8 + i]  = pack2(W1[64 + base], W1[65 + base]);
      sC1[qq][12 + i] = pack2(b1[base],      b1[base + 1]);
      sC2[qq][i]      = pack2(g1[base],      g1[base + 1]);
      sC2[qq][4 + i]  = pack2(be1[base],     be1[base + 1]);
      sC2[qq][8 + i]  = pack2(g2[base],      g2[base + 1]);
      sC2[qq][12 + i] = pack2(be2[base],     be2[base + 1]);
      sC3[qq][i]      = pack2(b2[base],      b2[base + 1]);
    }
  }

  // L2 A-frags in regs (8 VGPR): A[m=ch_out][k=ch_in] = W2[k][m]
  short4v a2[2][2];
#pragma unroll
  for (int t2 = 0; t2 < 2; ++t2)
#pragma unroll
    for (int h = 0; h < 2; ++h) {
      short4v v;
#pragma unroll
      for (int j = 0; j < 4; ++j)
        v[j] = (short)f2bf(W2[(4 * q + j + 16 * h) * 32 + ecol + 16 * t2]);
      a2[t2][h] = v;
    }

  __syncthreads();

  // front half: L1 -> LN1 -> L2 -> LN2 -> bh[2] (body identical to R7/R10)
  auto front = [&](float x0, float x1, float x2, short4v* bh) {
    const uint4v w1r0 = *(const uint4v*)&sC1[q][0];
    const uint4v w1r1 = *(const uint4v*)&sC1[q][4];
    const uint4v w1r2 = *(const uint4v*)&sC1[q][8];
    const uint4v b1v  = *(const uint4v*)&sC1[q][12];
    float hv[8];
#pragma unroll
    for (int i = 0; i < 4; ++i) {
      hv[2 * i]     = bflo2f(b1v[i]) + x0 * bflo2f(w1r0[i])
                    + x1 * bflo2f(w1r1[i]) + x2 * bflo2f(w1r2[i]);
      hv[2 * i + 1] = bfhi2f(b1v[i]) + x0 * bfhi2f(w1r0[i])
                    + x1 * bfhi2f(w1r1[i]) + x2 * bfhi2f(w1r2[i]);
    }
    {
      const uint4v g1v  = *(const uint4v*)&sC2[q][0];
      const uint4v be1v = *(const uint4v*)&sC2[q][4];
      ln_relu_pack(hv, g1v, be1v, bh);
    }
    {
      const uint4v b2v = *(const uint4v*)&sC3[q][0];
#pragma unroll
      for (int t2 = 0; t2 < 2; ++t2) {
        float4v c;
        c[0] = bflo2f(b2v[t2 * 2]);     c[1] = bfhi2f(b2v[t2 * 2]);
        c[2] = bflo2f(b2v[t2 * 2 + 1]); c[3] = bfhi2f(b2v[t2 * 2 + 1]);
        c = mfma16(a2[t2][0], bh[0], c);
        c = mfma16(a2[t2][1], bh[1], c);
        hv[t2 * 4 + 0] = c[0]; hv[t2 * 4 + 1] = c[1];
        hv[t2 * 4 + 2] = c[2]; hv[t2 * 4 + 3] = c[3];
      }
    }
    {
      const uint4v g2v  = *(const uint4v*)&sC2[q][8];
      const uint4v be2v = *(const uint4v*)&sC2[q][12];
      ln_relu_pack(hv, g2v, be2v, bh);
    }
  };

  const int gwave  = (blockIdx.x * blockDim.x + t) >> 6;
  const int nwaves = (gridDim.x * blockDim.x) >> 6;

  // Pair p = edges [p*32, p*32+32): A = first 16 (ecol), B = second 16.
  // Carried loop state (trimmed): indices + coords only.
  int pair = gwave;
  int ieA = 0, ieB = 0, oeA = 0, oeB = 0;
  bool validA = false, validB = false;
  float xA0 = 0.f, xA1 = 0.f, xA2 = 0.f, xB0 = 0.f, xB1 = 0.f, xB2 = 0.f;
  if (pair < npairs) {
    const int eA = pair * 32 + ecol, eB = pair * 32 + 16 + ecol;
    validA = eA < E;  validB = eB < E;
    const int sA = validA ? eA : 0, sB = validB ? eB : 0;
    ieA = in_edges[sA]; oeA = out_edges[sA];
    ieB = in_edges[sB]; oeB = out_edges[sB];
    xA0 = coords[3 * sA]; xA1 = coords[3 * sA + 1]; xA2 = coords[3 * sA + 2];
    xB0 = coords[3 * sB]; xB1 = coords[3 * sB + 1]; xB2 = coords[3 * sB + 2];
  }

  for (; pair < npairs; pair += nwaves) {
    // ---- issue current pair's feature gathers NOW (indices known);
    //      they land during the front halves, consumed in the epilogue ----
    const float4v f4A = *(const float4v*)(ef + (size_t)ieA * 16 + 4 * q);
    const float4v f4B = *(const float4v*)(ef + (size_t)ieB * 16 + 4 * q);

    // ---- prefetch next pair's indices + coords (carried, ~12 regs) ----
    const int pn = pair + nwaves;
    int ieAN = 0, ieBN = 0, oeAN = 0, oeBN = 0;
    bool validAN = false, validBN = false;
    float xA0N = 0.f, xA1N = 0.f, xA2N = 0.f, xB0N = 0.f, xB1N = 0.f, xB2N = 0.f;
    if (pn < npairs) {
      const int eA = pn * 32 + ecol, eB = pn * 32 + 16 + ecol;
      validAN = eA < E;  validBN = eB < E;
      const int sA = validAN ? eA : 0, sB = validBN ? eB : 0;
      ieAN = in_edges[sA]; oeAN = out_edges[sA];
      ieBN = in_edges[sB]; oeBN = out_edges[sB];
      xA0N = coords[3 * sA]; xA1N = coords[3 * sA + 1]; xA2N = coords[3 * sA + 2];
      xB0N = coords[3 * sB]; xB1N = coords[3 * sB + 1]; xB2N = coords[3 * sB + 2];
    }

    // CSR slots (atomic latency hides under the MLP)
    int posA = 0, posB = 0;
    if (SCATTER_MODE == 0 && q == 0) {
      if (validA) posA = atomicAdd(&cursor[oeA], 1);
      if (validB) posB = atomicAdd(&cursor[oeB], 1);
    }

    // ---- front halves: two independent chains interleave ----
    short4v bhA[2], bhB[2];
    front(xA0, xA1, xA2, bhA);
    front(xB0, xB1, xB2, bhB);

    const float sumfA = (f4A[0] + f4A[1]) + (f4A[2] + f4A[3]);
    const float sumfB = (f4B[0] + f4B[1]) + (f4B[2] + f4B[3]);

    // ---- L3 + epilogue: shared ds_reads feed both tiles ----
#pragma unroll
    for (int og = 0; og < 4; ++og) {
      float prA[4], prB[4];
#pragma unroll
      for (int r = 0; r < 4; ++r) {
        const int o = og * 4 + r;
        const uint4v av = *(const uint4v*)&sA3[(o * 64 + l) * 4];
        const float4v ci = *(const float4v*)&sB3f[(o * 4 + q) * 4];
        uint2v t0; t0[0] = av[0]; t0[1] = av[1];
        uint2v t1; t1[0] = av[2]; t1[1] = av[3];
        const short4v a30 = __builtin_bit_cast(short4v, t0);
        const short4v a31 = __builtin_bit_cast(short4v, t1);
        float4v cA = ci, cB = ci;
        cA = mfma16(a30, bhA[0], cA);
        cB = mfma16(a30, bhB[0], cB);
        cA = mfma16(a31, bhA[1], cA);
        cB = mfma16(a31, bhB[1], cB);
        float dA = 0.f, dB = 0.f;
#pragma unroll
        for (int j = 0; j < 4; ++j) {
          const float eA = __builtin_amdgcn_exp2f(cA[j]);
          const float eB = __builtin_amdgcn_exp2f(cB[j]);
          dA = fmaf(f4A[j], __builtin_amdgcn_rcpf(eA + 1.0f), dA);
          dB = fmaf(f4B[j], __builtin_amdgcn_rcpf(eB + 1.0f), dB);
        }
        prA[r] = fmaf(-2.0f, dA, sumfA);
        prB[r] = fmaf(-2.0f, dB, sumfB);
      }
#pragma unroll
      for (int r = 0; r < 4; ++r) {
        prA[r] += __shfl_xor(prA[r], 16);
        prA[r] += __shfl_xor(prA[r], 32);
        prB[r] += __shfl_xor(prB[r], 16);
        prB[r] += __shfl_xor(prB[r], 32);
      }
      if (SCATTER_MODE == 0) {
        if (q == 0 && validA) {
          float4v s = {prA[0], prA[1], prA[2], prA[3]};
          *(float4v*)(out_ch + (size_t)posA * 16 + og * 4) = s;
        }
        if (q == 0 && validB) {
          float4v s = {prB[0], prB[1], prB[2], prB[3]};
          *(float4v*)(out_ch + (size_t)posB * 16 + og * 4) = s;
        }
      } else {
        if (q == 0 && validA) {
#pragma unroll
          for (int r = 0; r < 4; ++r)
            atomicAdd(&out_ch[(size_t)oeA * 16 + og * 4 + r], prA[r]);
        }
        if (q == 0 && validB) {
#pragma unroll
          for (int r = 0; r < 4; ++r)
            atomicAdd(&out_ch[(size_t)oeB * 16 + og * 4 + r], prB[r]);
        }
      }
    }
    if (SCATTER_MODE == 1 && q == 0) {
      if (validA) atomicAdd(&aux[oeA], 1);
      if (validB) atomicAdd(&aux[oeB], 1);
    }

    // rotate carried state (indices + coords only)
    ieA = ieAN; ieB = ieBN; oeA = oeAN; oeB = oeBN;
    validA = validAN; validB = validBN;
    xA0 = xA0N; xA1 = xA1N; xA2 = xA2N; xB0 = xB0N; xB1 = xB1N; xB2 = xB2N;
  }
}

// ---------------- per-node reduce (CSR path, contiguous rows) ----------------

__global__ __launch_bounds__(256)
void nf_reduce(const float* __restrict__ out_ch, const int* __restrict__ counts,
               const int* __restrict__ offsets, float* __restrict__ out, int N) {
  const int gid = blockIdx.x * 16 + (threadIdx.x >> 4);
  const int o   = threadIdx.x & 15;
  if (gid >= N) return;
  const int deg = counts[gid];
  const int off = offsets[gid];
  float acc = 0.f;
  for (int d = 0; d < deg; ++d)
    acc += out_ch[(size_t)(off + d) * 16 + o];
  out[(size_t)gid * 16 + o] = acc / fmaxf((float)deg, 1.0f);
}

__global__ void nf_final(float* __restrict__ out, const int* __restrict__ counts, int n) {
  int i = blockIdx.x * blockDim.x + threadIdx.x;
  if (i < n) {
    float c = (float)counts[i >> 4];
    out[i] = out[i] / fmaxf(c, 1.0f);
  }
}

extern "C" void kernel_launch(void* const* d_in, const int* in_sizes, int n_in,
                              void* d_out, int out_size, void* d_ws, size_t ws_size,
                              hipStream_t stream) {
  const int*   in_edges  = (const int*)d_in[0];
  const int*   out_edges = (const int*)d_in[1];
  const float* ef        = (const float*)d_in[2];
  const float* coords    = (const float*)d_in[3];
  const float* W1  = (const float*)d_in[4];
  const float* b1  = (const float*)d_in[5];
  const float* g1  = (const float*)d_in[6];
  const float* be1 = (const float*)d_in[7];
  const float* W2  = (const float*)d_in[8];
  const float* b2  = (const float*)d_in[9];
  const float* g2  = (const float*)d_in[10];
  const float* be2 = (const float*)d_in[11];
  const float* W3  = (const float*)d_in[12];
  const float* b3  = (const float*)d_in[13];

  const int E = in_sizes[0];
  const int N = in_sizes[2] / 16;
  const int npairs = (E + 31) / 32;
  float* out = (float*)d_out;

  // ws: out_ch [16E f32] | counts [N] | offsets [N] | cursor [N] | total [1]
  const size_t need = ((size_t)E * 16 + 3 * (size_t)N + 1) * 4;

  if (ws_size >= need) {
    float* out_chv = (float*)d_ws;
    int*   counts  = (int*)(out_chv + (size_t)E * 16);
    int*   offsets = counts + N;
    int*   cursor  = offsets + N;
    int*   total   = cursor + N;

    hipMemsetAsync(counts, 0, ((size_t)3 * N + 1) * sizeof(int), stream);
    nf_hist<<<1024, 256, 0, stream>>>(out_edges, counts, E);
    nf_alloc<<<(N + 255) / 256, 256, 0, stream>>>(counts, offsets, cursor, total, N);
    nf_main<0><<<1024, 256, 0, stream>>>(in_edges, out_edges, ef, coords,
                                         W1, b1, g1, be1, W2, b2, g2, be2, W3, b3,
                                         out_chv, nullptr, cursor, E, npairs);
    nf_reduce<<<(N + 15) / 16, 256, 0, stream>>>(out_chv, counts, offsets, out, N);
  } else {
    int* counts = (int*)d_ws;
    hipMemsetAsync(out, 0, (size_t)out_size * sizeof(float), stream);
    hipMemsetAsync(counts, 0, (size_t)N * sizeof(int), stream);
    nf_main<1><<<1024, 256, 0, stream>>>(in_edges, out_edges, ef, coords,
                                         W1, b1, g1, be1, W2, b2, g2, be2, W3, b3,
                                         out, counts, nullptr, E, npairs);
    nf_final<<<(out_size + 255) / 256, 256, 0, stream>>>(out, counts, out_size);
  }
}

// Round 13
// 230.884 us; speedup vs baseline: 1.1096x; 1.0492x over previous
//
#include <hip/hip_runtime.h>

// NeuralFieldCosmo — R13: R7 nf_main (verified, 170us, spill-free) +
// bf16 out_ch intermediate (write 64->32MB, reduce reads halve) + vectorized
// hist + minimal memset.
// Dual-tile PARKED: R10/R11/R12 all spill ~18 regs at the 128-VGPR wall
// (allocator won't cross the 4->2 waves/SIMD cliff; waves_per_eu ignored).
// Ledger: cvt_pk inline-asm pack = NaN (R8/R9, banned). f2bf RNE pack
// verified R4-R12. MFMA 16x16x16bf16 layout verified. launch_bounds(256,2)
// + consts in LDS = spill-free at 128 VGPR (R6/R7).

typedef __attribute__((ext_vector_type(4))) short short4v;   // 4 bf16
typedef __attribute__((ext_vector_type(4))) float float4v;
typedef __attribute__((ext_vector_type(4))) unsigned uint4v;
typedef __attribute__((ext_vector_type(2))) unsigned uint2v;

constexpr float LN_EPS   = 1e-5f;
constexpr float LOG2E_X2 = 2.8853900817779268f;  // 2*log2(e)

// RNE float -> bf16 bits (verified R4-R12)
__device__ __forceinline__ unsigned f2bf(float x) {
  unsigned u = __builtin_bit_cast(unsigned, x);
  u += 0x7FFFu + ((u >> 16) & 1u);
  return u >> 16;
}
__device__ __forceinline__ unsigned pack2(float lo, float hi) {
  return f2bf(lo) | (f2bf(hi) << 16);
}
__device__ __forceinline__ float bflo2f(unsigned u) {
  return __builtin_bit_cast(float, u << 16);
}
__device__ __forceinline__ float bfhi2f(unsigned u) {
  return __builtin_bit_cast(float, u & 0xFFFF0000u);
}

__device__ __forceinline__ float4v mfma16(short4v a, short4v b, float4v c) {
#if __has_builtin(__builtin_amdgcn_mfma_f32_16x16x16bf16_1k)
  return __builtin_amdgcn_mfma_f32_16x16x16bf16_1k(a, b, c, 0, 0, 0);
#else
  float4v d;
  asm volatile("v_mfma_f32_16x16x16_bf16 %0, %1, %2, %3\n\ts_nop 7\n\ts_nop 7"
               : "=&v"(d) : "v"(a), "v"(b), "v"(c));
  return d;
#endif
}

// LN over 32 ch (8/lane across quads), affine (packed bf16 g,be), relu,
// pack to two K-half B-frags. IDENTICAL to R7 (verified).
__device__ __forceinline__ void ln_relu_pack(const float* hv, uint4v gp,
                                             uint4v bp, short4v* bh) {
  float sum = 0.f, ss = 0.f;
#pragma unroll
  for (int s = 0; s < 8; ++s) { sum += hv[s]; ss += hv[s] * hv[s]; }
  sum += __shfl_xor(sum, 16);  ss += __shfl_xor(ss, 16);
  sum += __shfl_xor(sum, 32);  ss += __shfl_xor(ss, 32);
  const float m   = sum * (1.0f / 32.0f);
  const float var = fmaxf(ss * (1.0f / 32.0f) - m * m, 0.f);
  const float rs  = rsqrtf(var + LN_EPS);
#pragma unroll
  for (int h = 0; h < 2; ++h) {
    short4v v;
#pragma unroll
    for (int j = 0; j < 4; ++j) {
      const int s = h * 4 + j;
      const float g  = (s & 1) ? bfhi2f(gp[s >> 1]) : bflo2f(gp[s >> 1]);
      const float be = (s & 1) ? bfhi2f(bp[s >> 1]) : bflo2f(bp[s >> 1]);
      float y = (hv[s] - m) * rs * g + be;
      v[j] = (short)f2bf(fmaxf(y, 0.f));
    }
    bh[h] = v;
  }
}

// ---------------- CSR build ----------------

// vectorized histogram: 4 edges/thread via int4
__global__ void nf_hist(const int* __restrict__ out_edges, int* __restrict__ counts, int E) {
  const int t4 = (blockIdx.x * blockDim.x + threadIdx.x) * 4;
  if (t4 + 3 < E) {
    const int4 v = *(const int4*)(out_edges + t4);
    atomicAdd(&counts[v.x], 1);
    atomicAdd(&counts[v.y], 1);
    atomicAdd(&counts[v.z], 1);
    atomicAdd(&counts[v.w], 1);
  } else {
    for (int i = t4; i < E; ++i) atomicAdd(&counts[out_edges[i]], 1);
  }
}

__global__ void nf_alloc(const int* __restrict__ counts, int* __restrict__ offsets,
                         int* __restrict__ cursor, int* __restrict__ total, int N) {
  const int i = blockIdx.x * blockDim.x + threadIdx.x;
  const int lane = threadIdx.x & 63;
  int c = (i < N) ? counts[i] : 0;
  int sc = c;
#pragma unroll
  for (int d = 1; d < 64; d <<= 1) {
    int v = __shfl_up(sc, d);
    if (lane >= d) sc += v;
  }
  const int excl = sc - c;
  const int wtot = __shfl(sc, 63);
  int base = 0;
  if (lane == 0) base = atomicAdd(total, wtot);
  base = __shfl(base, 0);
  if (i < N) {
    offsets[i] = base + excl;
    cursor[i]  = base + excl;
  }
}

// ---------------- main compute ----------------
// SCATTER_MODE: 0 = CSR-ordered bf16 stream, 1 = direct f32 atomics fallback

template <int SCATTER_MODE>
__global__ __launch_bounds__(256, 2)   // cap 256: spill-free at 128 (R6/R7)
void nf_main(const int* __restrict__ in_edges,
             const int* __restrict__ out_edges,
             const float* __restrict__ ef,
             const float* __restrict__ coords,
             const float* __restrict__ W1, const float* __restrict__ b1,
             const float* __restrict__ g1, const float* __restrict__ be1,
             const float* __restrict__ W2, const float* __restrict__ b2,
             const float* __restrict__ g2, const float* __restrict__ be2,
             const float* __restrict__ W3, const float* __restrict__ b3,
             void* __restrict__ out_ch,   // mode0: unsigned[E][8] bf16x2 ; mode1: float sums (d_out)
             int* __restrict__ aux,       // mode1: counts
             int* __restrict__ cursor,    // mode0: [N]
             int E, int ntiles)
{
  // W3 A-fragments (prescaled 2log2e), per (o, lane): 16B = 8 bf16 {k=4q+j+16h}
  __shared__ __align__(16) unsigned sA3[16 * 64 * 4];   // 16 KB
  __shared__ __align__(16) float    sB3f[16 * 4 * 4];   // 2log2e*b3, f32
  __shared__ __align__(16) unsigned sC1[4][16];  // w1p[3][4], b1p[4]
  __shared__ __align__(16) unsigned sC2[4][16];  // g1p, be1p, g2p, be2p
  __shared__ __align__(16) unsigned sC3[4][4];   // b2p

  const int t    = threadIdx.x;
  const int l    = t & 63;
  const int q    = l >> 4;     // lane quad (channel/row group)
  const int ecol = l & 15;     // edge column within tile

  // ---- one-time LDS staging (identical to R7, verified) ----
#pragma unroll
  for (int rep = 0; rep < 4; ++rep) {
    const int idx = rep * 256 + t;          // (o, lane)
    const int o = idx >> 6, ll = idx & 63;
    const int qq = ll >> 4, ec = ll & 15;
    uint4v w;
#pragma unroll
    for (int h = 0; h < 2; ++h)
#pragma unroll
      for (int jp = 0; jp < 2; ++jp) {
        const float lo = LOG2E_X2 * W3[(4 * qq + 2 * jp     + 16 * h) * 256 + o * 16 + ec];
        const float hi = LOG2E_X2 * W3[(4 * qq + 2 * jp + 1 + 16 * h) * 256 + o * 16 + ec];
        w[h * 2 + jp] = pack2(lo, hi);
      }
    *(uint4v*)&sA3[idx * 4] = w;
  }
  if (t < 64) {
    const int o = t >> 2, qq = t & 3;
    float4v bb;
#pragma unroll
    for (int r = 0; r < 4; ++r) bb[r] = LOG2E_X2 * b3[o * 16 + 4 * qq + r];
    *(float4v*)&sB3f[t * 4] = bb;
  }
  if (t < 4) {
    const int qq = t;
#pragma unroll
    for (int i = 0; i < 4; ++i) {
      const int base = (i < 2) ? (4 * qq + 2 * i) : (4 * qq + 16 + 2 * (i - 2));
      sC1[qq][i]      = pack2(W1[base],      W1[base + 1]);
      sC1[qq][4 + i]  = pack2(W1[32 + base], W1[33 + base]);
      sC1[qq][8 + i]  = pack2(W1[64 + base], W1[65 + base]);
      sC1[qq][12 + i] = pack2(b1[base],      b1[base + 1]);
      sC2[qq][i]      = pack2(g1[base],      g1[base + 1]);
      sC2[qq][4 + i]  = pack2(be1[base],     be1[base + 1]);
      sC2[qq][8 + i]  = pack2(g2[base],      g2[base + 1]);
      sC2[qq][12 + i] = pack2(be2[base],     be2[base + 1]);
      sC3[qq][i]      = pack2(b2[base],      b2[base + 1]);
    }
  }

  // L2 A-frags in regs (8 VGPR): A[m=ch_out][k=ch_in] = W2[k][m]
  short4v a2[2][2];
#pragma unroll
  for (int t2 = 0; t2 < 2; ++t2)
#pragma unroll
    for (int h = 0; h < 2; ++h) {
      short4v v;
#pragma unroll
      for (int j = 0; j < 4; ++j)
        v[j] = (short)f2bf(W2[(4 * q + j + 16 * h) * 32 + ecol + 16 * t2]);
      a2[t2][h] = v;
    }

  __syncthreads();

  const int gwave  = (blockIdx.x * blockDim.x + t) >> 6;
  const int nwaves = (gridDim.x * blockDim.x) >> 6;

  // ---- prologue: load tile-0 state ----
  int tile = gwave;
  bool valid = false; int eIdx = 0, oe = 0;
  float x0 = 0.f, x1 = 0.f, x2 = 0.f;
  float4v f4 = {};
  if (tile < ntiles) {
    eIdx  = tile * 16 + ecol;
    valid = eIdx < E;
    const int eS = valid ? eIdx : 0;
    const int ie = in_edges[eS]; oe = out_edges[eS];
    x0 = coords[3 * eS]; x1 = coords[3 * eS + 1]; x2 = coords[3 * eS + 2];
    f4 = *(const float4v*)(ef + (size_t)ie * 16 + 4 * q);
  }

  for (; tile < ntiles; tile += nwaves) {
    // ---- prefetch next tile's indices + coords ----
    const int tn = tile + nwaves;
    int eIdxN = 0, ieN = 0, oeN = 0; bool validN = false;
    float x0N = 0.f, x1N = 0.f, x2N = 0.f;
    if (tn < ntiles) {
      eIdxN  = tn * 16 + ecol;
      validN = eIdxN < E;
      const int eSN = validN ? eIdxN : 0;
      ieN = in_edges[eSN]; oeN = out_edges[eSN];
      x0N = coords[3 * eSN]; x1N = coords[3 * eSN + 1]; x2N = coords[3 * eSN + 2];
    }

    // CSR slot (atomic latency hides under the MLP)
    int pos = 0;
    if (SCATTER_MODE == 0 && q == 0 && valid)
      pos = atomicAdd(&cursor[oe], 1);

    // ---- L1: 3 -> 32 (consts via quad-broadcast LDS reads) ----
    const uint4v w1r0 = *(const uint4v*)&sC1[q][0];
    const uint4v w1r1 = *(const uint4v*)&sC1[q][4];
    const uint4v w1r2 = *(const uint4v*)&sC1[q][8];
    const uint4v b1v  = *(const uint4v*)&sC1[q][12];
    float hv[8];
#pragma unroll
    for (int i = 0; i < 4; ++i) {
      hv[2 * i]     = bflo2f(b1v[i]) + x0 * bflo2f(w1r0[i])
                    + x1 * bflo2f(w1r1[i]) + x2 * bflo2f(w1r2[i]);
      hv[2 * i + 1] = bfhi2f(b1v[i]) + x0 * bfhi2f(w1r0[i])
                    + x1 * bfhi2f(w1r1[i]) + x2 * bfhi2f(w1r2[i]);
    }
    short4v bh[2];
    {
      const uint4v g1v  = *(const uint4v*)&sC2[q][0];
      const uint4v be1v = *(const uint4v*)&sC2[q][4];
      ln_relu_pack(hv, g1v, be1v, bh);
    }

    // ---- L2 GEMM: 32->32 ----
    {
      const uint4v b2v = *(const uint4v*)&sC3[q][0];
#pragma unroll
      for (int t2 = 0; t2 < 2; ++t2) {
        float4v c;
        c[0] = bflo2f(b2v[t2 * 2]);     c[1] = bfhi2f(b2v[t2 * 2]);
        c[2] = bflo2f(b2v[t2 * 2 + 1]); c[3] = bfhi2f(b2v[t2 * 2 + 1]);
        c = mfma16(a2[t2][0], bh[0], c);
        c = mfma16(a2[t2][1], bh[1], c);
        hv[t2 * 4 + 0] = c[0]; hv[t2 * 4 + 1] = c[1];
        hv[t2 * 4 + 2] = c[2]; hv[t2 * 4 + 3] = c[3];
      }
    }
    {
      const uint4v g2v  = *(const uint4v*)&sC2[q][8];
      const uint4v be2v = *(const uint4v*)&sC2[q][12];
      ln_relu_pack(hv, g2v, be2v, bh);
    }

    // ---- prefetch next tile's feature gather (ieN landed by now) ----
    float4v f4N = {};
    if (tn < ntiles)
      f4N = *(const float4v*)(ef + (size_t)ieN * 16 + 4 * q);

    const float sumf = (f4[0] + f4[1]) + (f4[2] + f4[3]);

    // ---- L3 GEMM (y = 2log2e*(W3 h + b3)) + tanh-algebra epilogue ----
#pragma unroll
    for (int og = 0; og < 4; ++og) {
      float pr[4];
#pragma unroll
      for (int r = 0; r < 4; ++r) {
        const int o = og * 4 + r;
        const uint4v av = *(const uint4v*)&sA3[(o * 64 + l) * 4];
        float4v c = *(const float4v*)&sB3f[(o * 4 + q) * 4];
        uint2v t0; t0[0] = av[0]; t0[1] = av[1];
        uint2v t1; t1[0] = av[2]; t1[1] = av[3];
        const short4v a30 = __builtin_bit_cast(short4v, t0);
        const short4v a31 = __builtin_bit_cast(short4v, t1);
        c = mfma16(a30, bh[0], c);
        c = mfma16(a31, bh[1], c);
        float dot = 0.f;
#pragma unroll
        for (int j = 0; j < 4; ++j) {
          const float e = __builtin_amdgcn_exp2f(c[j]);
          dot = fmaf(f4[j], __builtin_amdgcn_rcpf(e + 1.0f), dot);
        }
        pr[r] = fmaf(-2.0f, dot, sumf);
      }
#pragma unroll
      for (int r = 0; r < 4; ++r) {
        pr[r] += __shfl_xor(pr[r], 16);
        pr[r] += __shfl_xor(pr[r], 32);
      }
      if (SCATTER_MODE == 0) {
        if (q == 0 && valid) {
          uint2v s;
          s[0] = pack2(pr[0], pr[1]);
          s[1] = pack2(pr[2], pr[3]);
          *(uint2v*)((unsigned*)out_ch + (size_t)pos * 8 + og * 2) = s;
        }
      } else {
        if (q == 0 && valid) {
          float* sums = (float*)out_ch;
#pragma unroll
          for (int r = 0; r < 4; ++r)
            atomicAdd(&sums[(size_t)oe * 16 + og * 4 + r], pr[r]);
        }
      }
    }
    if (SCATTER_MODE == 1) {
      if (q == 0 && valid) atomicAdd(&aux[oe], 1);
    }

    // rotate pipeline state
    eIdx = eIdxN; valid = validN; oe = oeN;
    x0 = x0N; x1 = x1N; x2 = x2N; f4 = f4N;
  }
}

// ---------------- per-node reduce (CSR path, bf16 rows) ----------------
// 8 threads/node, each handles 2 channels (one packed uint per edge-row).

__global__ __launch_bounds__(256)
void nf_reduce(const unsigned* __restrict__ out_chb, const int* __restrict__ counts,
               const int* __restrict__ offsets, float* __restrict__ out, int N) {
  const int gid = blockIdx.x * 32 + (threadIdx.x >> 3);  // node
  const int op  = threadIdx.x & 7;                       // channel pair
  if (gid >= N) return;
  const int deg = counts[gid];
  const int off = offsets[gid];
  float a0 = 0.f, a1 = 0.f;
  for (int d = 0; d < deg; ++d) {
    const unsigned u = out_chb[(size_t)(off + d) * 8 + op];
    a0 += bflo2f(u);
    a1 += bfhi2f(u);
  }
  const float inv = 1.0f / fmaxf((float)deg, 1.0f);
  float2 r; r.x = a0 * inv; r.y = a1 * inv;
  *(float2*)(out + (size_t)gid * 16 + 2 * op) = r;
}

// fallback divide
__global__ void nf_final(float* __restrict__ out, const int* __restrict__ counts, int n) {
  int i = blockIdx.x * blockDim.x + threadIdx.x;
  if (i < n) {
    float c = (float)counts[i >> 4];
    out[i] = out[i] / fmaxf(c, 1.0f);
  }
}

extern "C" void kernel_launch(void* const* d_in, const int* in_sizes, int n_in,
                              void* d_out, int out_size, void* d_ws, size_t ws_size,
                              hipStream_t stream) {
  const int*   in_edges  = (const int*)d_in[0];
  const int*   out_edges = (const int*)d_in[1];
  const float* ef        = (const float*)d_in[2];
  const float* coords    = (const float*)d_in[3];
  const float* W1  = (const float*)d_in[4];
  const float* b1  = (const float*)d_in[5];
  const float* g1  = (const float*)d_in[6];
  const float* be1 = (const float*)d_in[7];
  const float* W2  = (const float*)d_in[8];
  const float* b2  = (const float*)d_in[9];
  const float* g2  = (const float*)d_in[10];
  const float* be2 = (const float*)d_in[11];
  const float* W3  = (const float*)d_in[12];
  const float* b3  = (const float*)d_in[13];

  const int E = in_sizes[0];
  const int N = in_sizes[2] / 16;
  const int ntiles = (E + 15) / 16;
  float* out = (float*)d_out;

  // ws: out_chb [8E u32 bf16x2] | counts [N] | total [1] | offsets [N] | cursor [N]
  const size_t need = ((size_t)E * 8 + 3 * (size_t)N + 1) * 4;

  if (ws_size >= need) {
    unsigned* out_chb = (unsigned*)d_ws;
    int*      counts  = (int*)(out_chb + (size_t)E * 8);
    int*      total   = counts + N;
    int*      offsets = total + 1;
    int*      cursor  = offsets + N;

    // zero counts + total only (offsets/cursor fully written by nf_alloc)
    hipMemsetAsync(counts, 0, ((size_t)N + 1) * sizeof(int), stream);
    nf_hist<<<(E / 4 + 255) / 256 + 1, 256, 0, stream>>>(out_edges, counts, E);
    nf_alloc<<<(N + 255) / 256, 256, 0, stream>>>(counts, offsets, cursor, total, N);
    nf_main<0><<<2048, 256, 0, stream>>>(in_edges, out_edges, ef, coords,
                                         W1, b1, g1, be1, W2, b2, g2, be2, W3, b3,
                                         out_chb, nullptr, cursor, E, ntiles);
    nf_reduce<<<(N + 31) / 32, 256, 0, stream>>>(out_chb, counts, offsets, out, N);
  } else {
    // fallback: direct f32 atomics
    int* counts = (int*)d_ws;
    hipMemsetAsync(out, 0, (size_t)out_size * sizeof(float), stream);
    hipMemsetAsync(counts, 0, (size_t)N * sizeof(int), stream);
    nf_main<1><<<2048, 256, 0, stream>>>(in_edges, out_edges, ef, coords,
                                         W1, b1, g1, be1, W2, b2, g2, be2, W3, b3,
                                         out, counts, nullptr, E, ntiles);
    nf_final<<<(out_size + 255) / 256, 256, 0, stream>>>(out, counts, out_size);
  }
}

// Round 14
// 214.263 us; speedup vs baseline: 1.1957x; 1.0776x over previous
//
#include <hip/hip_runtime.h>

// NeuralFieldCosmo — R14: R13 base (verified 231us, absmax 0.047) + SKEWED
// SOFTWARE PIPELINE in nf_main: loop body = front(t+1) ∥ epilogue(t).
// The two phases are independent -> the front's serial LN/shfl/MFMA chains
// (the 46%-VALUBusy stall source) are filled by the epilogue's ILP-rich
// trans/FMA stream. Carried state: bh(4)+f4(4)+idx/coords(8) ≈ 16 regs —
// a third of dual-tile's cost (R10/R12 spilled at +30).
// Ledger: cvt_pk asm pack = NaN (banned). f2bf RNE verified R4-R13.
// MFMA 16x16x16bf16 layout verified. launch_bounds(256,2) + consts in LDS
// = spill-free at 128 VGPR. Spill tell = FETCH > 100 MB.

typedef __attribute__((ext_vector_type(4))) short short4v;   // 4 bf16
typedef __attribute__((ext_vector_type(4))) float float4v;
typedef __attribute__((ext_vector_type(4))) unsigned uint4v;
typedef __attribute__((ext_vector_type(2))) unsigned uint2v;

constexpr float LN_EPS   = 1e-5f;
constexpr float LOG2E_X2 = 2.8853900817779268f;  // 2*log2(e)

// RNE float -> bf16 bits (verified R4-R13)
__device__ __forceinline__ unsigned f2bf(float x) {
  unsigned u = __builtin_bit_cast(unsigned, x);
  u += 0x7FFFu + ((u >> 16) & 1u);
  return u >> 16;
}
__device__ __forceinline__ unsigned pack2(float lo, float hi) {
  return f2bf(lo) | (f2bf(hi) << 16);
}
__device__ __forceinline__ float bflo2f(unsigned u) {
  return __builtin_bit_cast(float, u << 16);
}
__device__ __forceinline__ float bfhi2f(unsigned u) {
  return __builtin_bit_cast(float, u & 0xFFFF0000u);
}

__device__ __forceinline__ float4v mfma16(short4v a, short4v b, float4v c) {
#if __has_builtin(__builtin_amdgcn_mfma_f32_16x16x16bf16_1k)
  return __builtin_amdgcn_mfma_f32_16x16x16bf16_1k(a, b, c, 0, 0, 0);
#else
  float4v d;
  asm volatile("v_mfma_f32_16x16x16_bf16 %0, %1, %2, %3\n\ts_nop 7\n\ts_nop 7"
               : "=&v"(d) : "v"(a), "v"(b), "v"(c));
  return d;
#endif
}

// LN over 32 ch (8/lane across quads), affine (packed bf16 g,be), relu,
// pack to two K-half B-frags. IDENTICAL to R7/R13 (verified).
__device__ __forceinline__ void ln_relu_pack(const float* hv, uint4v gp,
                                             uint4v bp, short4v* bh) {
  float sum = 0.f, ss = 0.f;
#pragma unroll
  for (int s = 0; s < 8; ++s) { sum += hv[s]; ss += hv[s] * hv[s]; }
  sum += __shfl_xor(sum, 16);  ss += __shfl_xor(ss, 16);
  sum += __shfl_xor(sum, 32);  ss += __shfl_xor(ss, 32);
  const float m   = sum * (1.0f / 32.0f);
  const float var = fmaxf(ss * (1.0f / 32.0f) - m * m, 0.f);
  const float rs  = rsqrtf(var + LN_EPS);
#pragma unroll
  for (int h = 0; h < 2; ++h) {
    short4v v;
#pragma unroll
    for (int j = 0; j < 4; ++j) {
      const int s = h * 4 + j;
      const float g  = (s & 1) ? bfhi2f(gp[s >> 1]) : bflo2f(gp[s >> 1]);
      const float be = (s & 1) ? bfhi2f(bp[s >> 1]) : bflo2f(bp[s >> 1]);
      float y = (hv[s] - m) * rs * g + be;
      v[j] = (short)f2bf(fmaxf(y, 0.f));
    }
    bh[h] = v;
  }
}

// ---------------- CSR build ----------------

// vectorized histogram: 4 edges/thread via int4
__global__ void nf_hist(const int* __restrict__ out_edges, int* __restrict__ counts, int E) {
  const int t4 = (blockIdx.x * blockDim.x + threadIdx.x) * 4;
  if (t4 + 3 < E) {
    const int4 v = *(const int4*)(out_edges + t4);
    atomicAdd(&counts[v.x], 1);
    atomicAdd(&counts[v.y], 1);
    atomicAdd(&counts[v.z], 1);
    atomicAdd(&counts[v.w], 1);
  } else {
    for (int i = t4; i < E; ++i) atomicAdd(&counts[out_edges[i]], 1);
  }
}

__global__ void nf_alloc(const int* __restrict__ counts, int* __restrict__ offsets,
                         int* __restrict__ cursor, int* __restrict__ total, int N) {
  const int i = blockIdx.x * blockDim.x + threadIdx.x;
  const int lane = threadIdx.x & 63;
  int c = (i < N) ? counts[i] : 0;
  int sc = c;
#pragma unroll
  for (int d = 1; d < 64; d <<= 1) {
    int v = __shfl_up(sc, d);
    if (lane >= d) sc += v;
  }
  const int excl = sc - c;
  const int wtot = __shfl(sc, 63);
  int base = 0;
  if (lane == 0) base = atomicAdd(total, wtot);
  base = __shfl(base, 0);
  if (i < N) {
    offsets[i] = base + excl;
    cursor[i]  = base + excl;
  }
}

// ---------------- main compute ----------------
// SCATTER_MODE: 0 = CSR-ordered bf16 stream, 1 = direct f32 atomics fallback

template <int SCATTER_MODE>
__global__ __launch_bounds__(256, 2)   // cap 256: spill-free at 128 (R6/R7/R13)
void nf_main(const int* __restrict__ in_edges,
             const int* __restrict__ out_edges,
             const float* __restrict__ ef,
             const float* __restrict__ coords,
             const float* __restrict__ W1, const float* __restrict__ b1,
             const float* __restrict__ g1, const float* __restrict__ be1,
             const float* __restrict__ W2, const float* __restrict__ b2,
             const float* __restrict__ g2, const float* __restrict__ be2,
             const float* __restrict__ W3, const float* __restrict__ b3,
             void* __restrict__ out_ch,   // mode0: unsigned[E][8] bf16x2 ; mode1: float sums (d_out)
             int* __restrict__ aux,       // mode1: counts
             int* __restrict__ cursor,    // mode0: [N]
             int E, int ntiles)
{
  // W3 A-fragments (prescaled 2log2e), per (o, lane): 16B = 8 bf16 {k=4q+j+16h}
  __shared__ __align__(16) unsigned sA3[16 * 64 * 4];   // 16 KB
  __shared__ __align__(16) float    sB3f[16 * 4 * 4];   // 2log2e*b3, f32
  __shared__ __align__(16) unsigned sC1[4][16];  // w1p[3][4], b1p[4]
  __shared__ __align__(16) unsigned sC2[4][16];  // g1p, be1p, g2p, be2p
  __shared__ __align__(16) unsigned sC3[4][4];   // b2p

  const int t    = threadIdx.x;
  const int l    = t & 63;
  const int q    = l >> 4;     // lane quad (channel/row group)
  const int ecol = l & 15;     // edge column within tile

  // ---- one-time LDS staging (identical to R7/R13, verified) ----
#pragma unroll
  for (int rep = 0; rep < 4; ++rep) {
    const int idx = rep * 256 + t;          // (o, lane)
    const int o = idx >> 6, ll = idx & 63;
    const int qq = ll >> 4, ec = ll & 15;
    uint4v w;
#pragma unroll
    for (int h = 0; h < 2; ++h)
#pragma unroll
      for (int jp = 0; jp < 2; ++jp) {
        const float lo = LOG2E_X2 * W3[(4 * qq + 2 * jp     + 16 * h) * 256 + o * 16 + ec];
        const float hi = LOG2E_X2 * W3[(4 * qq + 2 * jp + 1 + 16 * h) * 256 + o * 16 + ec];
        w[h * 2 + jp] = pack2(lo, hi);
      }
    *(uint4v*)&sA3[idx * 4] = w;
  }
  if (t < 64) {
    const int o = t >> 2, qq = t & 3;
    float4v bb;
#pragma unroll
    for (int r = 0; r < 4; ++r) bb[r] = LOG2E_X2 * b3[o * 16 + 4 * qq + r];
    *(float4v*)&sB3f[t * 4] = bb;
  }
  if (t < 4) {
    const int qq = t;
#pragma unroll
    for (int i = 0; i < 4; ++i) {
      const int base = (i < 2) ? (4 * qq + 2 * i) : (4 * qq + 16 + 2 * (i - 2));
      sC1[qq][i]      = pack2(W1[base],      W1[base + 1]);
      sC1[qq][4 + i]  = pack2(W1[32 + base], W1[33 + base]);
      sC1[qq][8 + i]  = pack2(W1[64 + base], W1[65 + base]);
      sC1[qq][12 + i] = pack2(b1[base],      b1[base + 1]);
      sC2[qq][i]      = pack2(g1[base],      g1[base + 1]);
      sC2[qq][4 + i]  = pack2(be1[base],     be1[base + 1]);
      sC2[qq][8 + i]  = pack2(g2[base],      g2[base + 1]);
      sC2[qq][12 + i] = pack2(be2[base],     be2[base + 1]);
      sC3[qq][i]      = pack2(b2[base],      b2[base + 1]);
    }
  }

  // L2 A-frags in regs (8 VGPR): A[m=ch_out][k=ch_in] = W2[k][m]
  short4v a2[2][2];
#pragma unroll
  for (int t2 = 0; t2 < 2; ++t2)
#pragma unroll
    for (int h = 0; h < 2; ++h) {
      short4v v;
#pragma unroll
      for (int j = 0; j < 4; ++j)
        v[j] = (short)f2bf(W2[(4 * q + j + 16 * h) * 32 + ecol + 16 * t2]);
      a2[t2][h] = v;
    }

  __syncthreads();

  // front: L1 -> LN1 -> L2 -> LN2 -> bh[2] (numerics identical to R7/R13)
  auto front = [&](float x0, float x1, float x2, short4v* bh) {
    const uint4v w1r0 = *(const uint4v*)&sC1[q][0];
    const uint4v w1r1 = *(const uint4v*)&sC1[q][4];
    const uint4v w1r2 = *(const uint4v*)&sC1[q][8];
    const uint4v b1v  = *(const uint4v*)&sC1[q][12];
    float hv[8];
#pragma unroll
    for (int i = 0; i < 4; ++i) {
      hv[2 * i]     = bflo2f(b1v[i]) + x0 * bflo2f(w1r0[i])
                    + x1 * bflo2f(w1r1[i]) + x2 * bflo2f(w1r2[i]);
      hv[2 * i + 1] = bfhi2f(b1v[i]) + x0 * bfhi2f(w1r0[i])
                    + x1 * bfhi2f(w1r1[i]) + x2 * bfhi2f(w1r2[i]);
    }
    {
      const uint4v g1v  = *(const uint4v*)&sC2[q][0];
      const uint4v be1v = *(const uint4v*)&sC2[q][4];
      ln_relu_pack(hv, g1v, be1v, bh);
    }
    {
      const uint4v b2v = *(const uint4v*)&sC3[q][0];
#pragma unroll
      for (int t2 = 0; t2 < 2; ++t2) {
        float4v c;
        c[0] = bflo2f(b2v[t2 * 2]);     c[1] = bfhi2f(b2v[t2 * 2]);
        c[2] = bflo2f(b2v[t2 * 2 + 1]); c[3] = bfhi2f(b2v[t2 * 2 + 1]);
        c = mfma16(a2[t2][0], bh[0], c);
        c = mfma16(a2[t2][1], bh[1], c);
        hv[t2 * 4 + 0] = c[0]; hv[t2 * 4 + 1] = c[1];
        hv[t2 * 4 + 2] = c[2]; hv[t2 * 4 + 3] = c[3];
      }
    }
    {
      const uint4v g2v  = *(const uint4v*)&sC2[q][8];
      const uint4v be2v = *(const uint4v*)&sC2[q][12];
      ln_relu_pack(hv, g2v, be2v, bh);
    }
  };

  const int gwave  = (blockIdx.x * blockDim.x + t) >> 6;
  const int nwaves = (gridDim.x * blockDim.x) >> 6;

  // ---- skewed-pipeline prologue ----
  // Stage tile t0 = gwave fully: idx/coords -> f4 gather -> front -> bh_cur.
  int tile = gwave;
  bool validC = false; int oeC = 0;
  short4v bhC[2] = {};
  float4v f4C = {};
  // next-tile (t+1) prefetched state
  bool validN = false; int ieN = 0, oeN = 0;
  float xN0 = 0.f, xN1 = 0.f, xN2 = 0.f;

  if (tile < ntiles) {
    const int eI = tile * 16 + ecol;
    validC = eI < E;
    const int eS = validC ? eI : 0;
    const int ie = in_edges[eS]; oeC = out_edges[eS];
    const float x0 = coords[3 * eS], x1 = coords[3 * eS + 1], x2 = coords[3 * eS + 2];
    f4C = *(const float4v*)(ef + (size_t)ie * 16 + 4 * q);
    front(x0, x1, x2, bhC);
  }
  if (tile + nwaves < ntiles) {
    const int eI = (tile + nwaves) * 16 + ecol;
    validN = eI < E;
    const int eS = validN ? eI : 0;
    ieN = in_edges[eS]; oeN = out_edges[eS];
    xN0 = coords[3 * eS]; xN1 = coords[3 * eS + 1]; xN2 = coords[3 * eS + 2];
  }

  for (; tile < ntiles; tile += nwaves) {
    const int tn  = tile + nwaves;       // tile whose front runs this iter
    const int tnn = tile + 2 * nwaves;   // tile whose idx/coords prefetch now

    // ---- issue next tile's feature gather (consumed next iteration) ----
    float4v f4N = {};
    if (tn < ntiles)
      f4N = *(const float4v*)(ef + (size_t)ieN * 16 + 4 * q);

    // ---- CSR slot for CURRENT tile (latency hides under front+epilogue) ----
    int pos = 0;
    if (SCATTER_MODE == 0 && q == 0 && validC)
      pos = atomicAdd(&cursor[oeC], 1);

    // ---- prefetch tile t+2 idx/coords ----
    bool validNN = false; int ieNN = 0, oeNN = 0;
    float xNN0 = 0.f, xNN1 = 0.f, xNN2 = 0.f;
    if (tnn < ntiles) {
      const int eI = tnn * 16 + ecol;
      validNN = eI < E;
      const int eS = validNN ? eI : 0;
      ieNN = in_edges[eS]; oeNN = out_edges[eS];
      xNN0 = coords[3 * eS]; xNN1 = coords[3 * eS + 1]; xNN2 = coords[3 * eS + 2];
    }

    // ---- front(t+1): long-latency chains issue first... ----
    short4v bhN[2] = {};
    if (tn < ntiles)
      front(xN0, xN1, xN2, bhN);

    // ---- ...epilogue(t): independent ILP-rich stream fills the stalls ----
    const float sumf = (f4C[0] + f4C[1]) + (f4C[2] + f4C[3]);
#pragma unroll
    for (int og = 0; og < 4; ++og) {
      float pr[4];
#pragma unroll
      for (int r = 0; r < 4; ++r) {
        const int o = og * 4 + r;
        const uint4v av = *(const uint4v*)&sA3[(o * 64 + l) * 4];
        float4v c = *(const float4v*)&sB3f[(o * 4 + q) * 4];
        uint2v t0; t0[0] = av[0]; t0[1] = av[1];
        uint2v t1; t1[0] = av[2]; t1[1] = av[3];
        const short4v a30 = __builtin_bit_cast(short4v, t0);
        const short4v a31 = __builtin_bit_cast(short4v, t1);
        c = mfma16(a30, bhC[0], c);
        c = mfma16(a31, bhC[1], c);
        float dot = 0.f;
#pragma unroll
        for (int j = 0; j < 4; ++j) {
          const float e = __builtin_amdgcn_exp2f(c[j]);
          dot = fmaf(f4C[j], __builtin_amdgcn_rcpf(e + 1.0f), dot);
        }
        pr[r] = fmaf(-2.0f, dot, sumf);
      }
#pragma unroll
      for (int r = 0; r < 4; ++r) {
        pr[r] += __shfl_xor(pr[r], 16);
        pr[r] += __shfl_xor(pr[r], 32);
      }
      if (SCATTER_MODE == 0) {
        if (q == 0 && validC) {
          uint2v s;
          s[0] = pack2(pr[0], pr[1]);
          s[1] = pack2(pr[2], pr[3]);
          *(uint2v*)((unsigned*)out_ch + (size_t)pos * 8 + og * 2) = s;
        }
      } else {
        if (q == 0 && validC) {
          float* sums = (float*)out_ch;
#pragma unroll
          for (int r = 0; r < 4; ++r)
            atomicAdd(&sums[(size_t)oeC * 16 + og * 4 + r], pr[r]);
        }
      }
    }
    if (SCATTER_MODE == 1) {
      if (q == 0 && validC) atomicAdd(&aux[oeC], 1);
    }

    // ---- rotate pipeline state ----
    bhC[0] = bhN[0]; bhC[1] = bhN[1];
    f4C = f4N; oeC = oeN; validC = validN;
    ieN = ieNN; oeN = oeNN; validN = validNN;
    xN0 = xNN0; xN1 = xNN1; xN2 = xNN2;
  }
}

// ---------------- per-node reduce (CSR path, bf16 rows) ----------------
// 8 threads/node, each handles 2 channels (one packed uint per edge-row).

__global__ __launch_bounds__(256)
void nf_reduce(const unsigned* __restrict__ out_chb, const int* __restrict__ counts,
               const int* __restrict__ offsets, float* __restrict__ out, int N) {
  const int gid = blockIdx.x * 32 + (threadIdx.x >> 3);  // node
  const int op  = threadIdx.x & 7;                       // channel pair
  if (gid >= N) return;
  const int deg = counts[gid];
  const int off = offsets[gid];
  float a0 = 0.f, a1 = 0.f;
  for (int d = 0; d < deg; ++d) {
    const unsigned u = out_chb[(size_t)(off + d) * 8 + op];
    a0 += bflo2f(u);
    a1 += bfhi2f(u);
  }
  const float inv = 1.0f / fmaxf((float)deg, 1.0f);
  float2 r; r.x = a0 * inv; r.y = a1 * inv;
  *(float2*)(out + (size_t)gid * 16 + 2 * op) = r;
}

// fallback divide
__global__ void nf_final(float* __restrict__ out, const int* __restrict__ counts, int n) {
  int i = blockIdx.x * blockDim.x + threadIdx.x;
  if (i < n) {
    float c = (float)counts[i >> 4];
    out[i] = out[i] / fmaxf(c, 1.0f);
  }
}

extern "C" void kernel_launch(void* const* d_in, const int* in_sizes, int n_in,
                              void* d_out, int out_size, void* d_ws, size_t ws_size,
                              hipStream_t stream) {
  const int*   in_edges  = (const int*)d_in[0];
  const int*   out_edges = (const int*)d_in[1];
  const float* ef        = (const float*)d_in[2];
  const float* coords    = (const float*)d_in[3];
  const float* W1  = (const float*)d_in[4];
  const float* b1  = (const float*)d_in[5];
  const float* g1  = (const float*)d_in[6];
  const float* be1 = (const float*)d_in[7];
  const float* W2  = (const float*)d_in[8];
  const float* b2  = (const float*)d_in[9];
  const float* g2  = (const float*)d_in[10];
  const float* be2 = (const float*)d_in[11];
  const float* W3  = (const float*)d_in[12];
  const float* b3  = (const float*)d_in[13];

  const int E = in_sizes[0];
  const int N = in_sizes[2] / 16;
  const int ntiles = (E + 15) / 16;
  float* out = (float*)d_out;

  // ws: out_chb [8E u32 bf16x2] | counts [N] | total [1] | offsets [N] | cursor [N]
  const size_t need = ((size_t)E * 8 + 3 * (size_t)N + 1) * 4;

  if (ws_size >= need) {
    unsigned* out_chb = (unsigned*)d_ws;
    int*      counts  = (int*)(out_chb + (size_t)E * 8);
    int*      total   = counts + N;
    int*      offsets = total + 1;
    int*      cursor  = offsets + N;

    // zero counts + total only (offsets/cursor fully written by nf_alloc)
    hipMemsetAsync(counts, 0, ((size_t)N + 1) * sizeof(int), stream);
    nf_hist<<<(E / 4 + 255) / 256 + 1, 256, 0, stream>>>(out_edges, counts, E);
    nf_alloc<<<(N + 255) / 256, 256, 0, stream>>>(counts, offsets, cursor, total, N);
    nf_main<0><<<2048, 256, 0, stream>>>(in_edges, out_edges, ef, coords,
                                         W1, b1, g1, be1, W2, b2, g2, be2, W3, b3,
                                         out_chb, nullptr, cursor, E, ntiles);
    nf_reduce<<<(N + 31) / 32, 256, 0, stream>>>(out_chb, counts, offsets, out, N);
  } else {
    // fallback: direct f32 atomics
    int* counts = (int*)d_ws;
    hipMemsetAsync(out, 0, (size_t)out_size * sizeof(float), stream);
    hipMemsetAsync(counts, 0, (size_t)N * sizeof(int), stream);
    nf_main<1><<<2048, 256, 0, stream>>>(in_edges, out_edges, ef, coords,
                                         W1, b1, g1, be1, W2, b2, g2, be2, W3, b3,
                                         out, counts, nullptr, E, ntiles);
    nf_final<<<(out_size + 255) / 256, 256, 0, stream>>>(out, counts, out_size);
  }
}